// Round 1
// baseline (68.781 us; speedup 1.0000x reference)
//
#include <hip/hip_runtime.h>

// PhysicsInformedLoss on (16,3,1024,512) f32 y_hat + (16,2,1024,512) i32 x_in.
// Memory-bound: ~134 MB unique traffic -> ~21 us floor at 6.3 TB/s.

namespace {
constexpr int NXc  = 1024;
constexpr int NYc  = 512;
constexpr int NXYc = NXc * NYc;     // 2^19
constexpr int NBc  = 16;
constexpr int NBLK = 1024;
constexpr int NTHR = 256;
constexpr int NACC = 10;
// acc layout: 0 s_div2, 1 s_resx2, 2 s_resy2, 3 n_interior,
//             4 s_noslip, 5 n_noslip, 6 s_inlet, 7 n_inlet, 8 s_outlet, 9 n_outlet
}

__global__ __launch_bounds__(NTHR) void pil_main(const float* __restrict__ y,
                                                 const int* __restrict__ xin,
                                                 double* __restrict__ partial) {
  constexpr double DXd = 0.26 / 1023.0;
  constexpr double DYd = 0.12 / 511.0;
  const float INV2DX = (float)(1.0 / (2.0 * DXd));
  const float INV2DY = (float)(1.0 / (2.0 * DYd));
  const float INVDX2 = (float)(1.0 / (DXd * DXd));
  const float INVDY2 = (float)(1.0 / (DYd * DYd));
  constexpr float NU = 1e-4f;
  constexpr float U_INLET = 0.1f;

  float a[NACC];
#pragma unroll
  for (int k = 0; k < NACC; ++k) a[k] = 0.f;

  const int total = NBc * NXYc;
  const int stride = gridDim.x * blockDim.x;
  for (int idx = blockIdx.x * blockDim.x + threadIdx.x; idx < total; idx += stride) {
    const int b  = idx >> 19;           // NXY = 2^19
    const int ij = idx & (NXYc - 1);
    const int i  = ij >> 9;             // NY = 2^9
    const int j  = ij & (NYc - 1);

    const int r = xin[((b << 1) + 1) * NXYc + ij];

    const float* __restrict__ ux = y + (size_t)b * 3 * NXYc;
    const float* __restrict__ uy = ux + NXYc;
    const float* __restrict__ pp = ux + 2 * NXYc;

    // edge-clamped neighbor offsets (matches mode='edge' padding)
    const int xm = (i > 0)       ? ij - NYc : ij;
    const int xp = (i < NXc - 1) ? ij + NYc : ij;
    const int ym = (j > 0)       ? ij - 1   : ij;
    const int yp = (j < NYc - 1) ? ij + 1   : ij;

    const float uxc  = ux[ij];
    const float uxxm = ux[xm], uxxp = ux[xp], uxym = ux[ym], uxyp = ux[yp];
    const float uyc  = uy[ij];
    const float uyxm = uy[xm], uyxp = uy[xp], uyym = uy[ym], uyyp = uy[yp];
    const float pxm  = pp[xm], pxp  = pp[xp], pym  = pp[ym], pyp  = pp[yp];

    const float ddx_ux = (uxxp - uxxm) * INV2DX;
    const float ddy_ux = (uxyp - uxym) * INV2DY;
    const float ddx_uy = (uyxp - uyxm) * INV2DX;
    const float ddy_uy = (uyyp - uyym) * INV2DY;

    const bool interior = (r >= 1) & (i >= 1) & (i <= NXc - 2) & (j >= 1) & (j <= NYc - 2);
    if (interior) {
      const float dv    = ddx_ux + ddy_uy;
      const float d2xux = (uxxp - 2.f * uxc + uxxm) * INVDX2;
      const float d2yux = (uxyp - 2.f * uxc + uxym) * INVDY2;
      const float d2xuy = (uyxp - 2.f * uyc + uyxm) * INVDX2;
      const float d2yuy = (uyyp - 2.f * uyc + uyym) * INVDY2;
      const float ddx_p = (pxp - pxm) * INV2DX;
      const float ddy_p = (pyp - pym) * INV2DY;
      const float rx = uxc * ddx_ux + uyc * ddy_ux + ddx_p - NU * (d2xux + d2yux);
      const float ry = uxc * ddx_uy + uyc * ddy_uy + ddy_p - NU * (d2xuy + d2yuy);
      a[0] += dv * dv;
      a[1] += rx * rx;
      a[2] += ry * ry;
      a[3] += 1.f;
    }
    if ((r == 0) | (r == 2)) {  // noslip = obstacle | wall
      a[4] += uxc * uxc + uyc * uyc;
      a[5] += 1.f;
    }
    if (r == 3) {               // inlet
      const float d = uxc - U_INLET;
      a[6] += d * d + uyc * uyc;
      a[7] += 1.f;
    }
    if (r == 4) {               // outlet
      a[8] += ddx_ux * ddx_ux;
      a[9] += 1.f;
    }
  }

  // wave-64 shuffle reduction per accumulator
#pragma unroll
  for (int k = 0; k < NACC; ++k) {
    float v = a[k];
#pragma unroll
    for (int off = 32; off > 0; off >>= 1) v += __shfl_down(v, off, 64);
    a[k] = v;
  }

  __shared__ double sacc[NTHR / 64][NACC];
  const int lane = threadIdx.x & 63;
  const int wave = threadIdx.x >> 6;
  if (lane == 0) {
#pragma unroll
    for (int k = 0; k < NACC; ++k) sacc[wave][k] = (double)a[k];
  }
  __syncthreads();
  if (threadIdx.x < NACC) {
    double s = 0.0;
#pragma unroll
    for (int w = 0; w < NTHR / 64; ++w) s += sacc[w][threadIdx.x];
    partial[threadIdx.x * gridDim.x + blockIdx.x] = s;  // SoA [NACC][gridDim]
  }
}

__global__ __launch_bounds__(NTHR) void pil_finalize(const double* __restrict__ partial,
                                                     float* __restrict__ out) {
  __shared__ double sw[NACC][NTHR / 64];
  const int t = threadIdx.x;
  const int lane = t & 63, wave = t >> 6;
#pragma unroll
  for (int k = 0; k < NACC; ++k) {
    double v = 0.0;
    for (int b = t; b < NBLK; b += NTHR) v += partial[k * NBLK + b];
#pragma unroll
    for (int off = 32; off > 0; off >>= 1) v += __shfl_down(v, off, 64);
    if (lane == 0) sw[k][wave] = v;
  }
  __syncthreads();
  if (t == 0) {
    double acc[NACC];
#pragma unroll
    for (int k = 0; k < NACC; ++k) {
      double s = 0.0;
#pragma unroll
      for (int w = 0; w < NTHR / 64; ++w) s += sw[k][w];
      acc[k] = s;
    }
    const double l_cont = acc[0] / fmax(acc[3], 1.0);
    const double l_mom  = (acc[1] + acc[2]) / fmax(acc[3], 1.0);
    const double l_bc   = acc[4] / fmax(acc[5], 1.0)
                        + acc[6] / fmax(acc[7], 1.0)
                        + acc[8] / fmax(acc[9], 1.0);
    const double total  = 1.0 * l_cont + 0.1 * l_mom + 1.0 * l_bc;
    out[0] = (float)l_cont;
    out[1] = (float)l_mom;
    out[2] = (float)l_bc;
    out[3] = (float)total;
  }
}

extern "C" void kernel_launch(void* const* d_in, const int* in_sizes, int n_in,
                              void* d_out, int out_size, void* d_ws, size_t ws_size,
                              hipStream_t stream) {
  const float* y   = (const float*)d_in[0];   // y_hat (16,3,1024,512) f32
  const int*   xin = (const int*)d_in[1];     // x_in  (16,2,1024,512) i32
  double* partial  = (double*)d_ws;           // needs NACC*NBLK*8 = 80 KB

  pil_main<<<NBLK, NTHR, 0, stream>>>(y, xin, partial);
  pil_finalize<<<1, NTHR, 0, stream>>>(partial, (float*)d_out);
}

// Round 2
// 66.560 us; speedup vs baseline: 1.0334x; 1.0334x over previous
//
#include <hip/hip_runtime.h>

// PhysicsInformedLoss on (16,3,1024,512) f32 y_hat + (16,2,1024,512) i32 x_in.
// Memory-bound: ~134 MB unique traffic -> ~21 us floor at 6.3 TB/s.
// R2: float4-vectorized along j (4 pts/thread), int4 region load, 2048-block grid.

namespace {
constexpr int NXc  = 1024;
constexpr int NYc  = 512;
constexpr int NXYc = NXc * NYc;     // 2^19
constexpr int NBc  = 16;
constexpr int NTHR = 256;
constexpr int NACC = 10;
constexpr int MAXBLK = 2048;
// acc layout: 0 s_div2, 1 s_resx2, 2 s_resy2, 3 n_interior,
//             4 s_noslip, 5 n_noslip, 6 s_inlet, 7 n_inlet, 8 s_outlet, 9 n_outlet
}

__global__ __launch_bounds__(NTHR) void pil_main(const float* __restrict__ y,
                                                 const int* __restrict__ xin,
                                                 double* __restrict__ partial) {
  constexpr double DXd = 0.26 / 1023.0;
  constexpr double DYd = 0.12 / 511.0;
  const float INV2DX = (float)(1.0 / (2.0 * DXd));
  const float INV2DY = (float)(1.0 / (2.0 * DYd));
  const float INVDX2 = (float)(1.0 / (DXd * DXd));
  const float INVDY2 = (float)(1.0 / (DYd * DYd));
  constexpr float NU = 1e-4f;
  constexpr float U_INLET = 0.1f;

  float a[NACC];
#pragma unroll
  for (int k = 0; k < NACC; ++k) a[k] = 0.f;

  const int vec_total = (NBc * NXYc) >> 2;   // 2^21 float4-groups
  const int stride = gridDim.x * blockDim.x;
  for (int v = blockIdx.x * blockDim.x + threadIdx.x; v < vec_total; v += stride) {
    const int b   = v >> 17;                 // NXY/4 = 2^17 per batch
    const int rem = v & ((1 << 17) - 1);
    const int i   = rem >> 7;                // NY/4 = 128 groups per row
    const int j0  = (rem & 127) << 2;
    const int ij0 = (i << 9) + j0;

    const float* __restrict__ ux = y + (size_t)b * 3 * NXYc;
    const float* __restrict__ uy = ux + NXYc;
    const float* __restrict__ pp = uy + NXYc;

    const int4 rv = *reinterpret_cast<const int4*>(xin + (((size_t)(b << 1) + 1) << 19) + ij0);

    const int dxm = (i > 0)       ? -NYc : 0;   // edge-clamped x neighbors
    const int dxp = (i < NXc - 1) ?  NYc : 0;

    const float4 uxc = *reinterpret_cast<const float4*>(ux + ij0);
    const float4 uxm = *reinterpret_cast<const float4*>(ux + ij0 + dxm);
    const float4 uxp = *reinterpret_cast<const float4*>(ux + ij0 + dxp);
    const float4 uyc = *reinterpret_cast<const float4*>(uy + ij0);
    const float4 uym = *reinterpret_cast<const float4*>(uy + ij0 + dxm);
    const float4 uyp = *reinterpret_cast<const float4*>(uy + ij0 + dxp);
    const float4 pxm = *reinterpret_cast<const float4*>(pp + ij0 + dxm);
    const float4 pxp = *reinterpret_cast<const float4*>(pp + ij0 + dxp);
    const float4 pc  = *reinterpret_cast<const float4*>(pp + ij0);

    const bool jlo = (j0 > 0), jhi = (j0 + 4 < NYc);
    const float ux_l = jlo ? ux[ij0 - 1] : uxc.x;   // y-edge clamp
    const float ux_r = jhi ? ux[ij0 + 4] : uxc.w;
    const float uy_l = jlo ? uy[ij0 - 1] : uyc.x;
    const float uy_r = jhi ? uy[ij0 + 4] : uyc.w;
    const float p_l  = jlo ? pp[ij0 - 1] : pc.x;
    const float p_r  = jhi ? pp[ij0 + 4] : pc.w;

    const float uxcA[4] = {uxc.x, uxc.y, uxc.z, uxc.w};
    const float uxmA[4] = {uxm.x, uxm.y, uxm.z, uxm.w};
    const float uxpA[4] = {uxp.x, uxp.y, uxp.z, uxp.w};
    const float uycA[4] = {uyc.x, uyc.y, uyc.z, uyc.w};
    const float uymA[4] = {uym.x, uym.y, uym.z, uym.w};
    const float uypA[4] = {uyp.x, uyp.y, uyp.z, uyp.w};
    const float pcA[4]  = {pc.x,  pc.y,  pc.z,  pc.w};
    const float pxmA[4] = {pxm.x, pxm.y, pxm.z, pxm.w};
    const float pxpA[4] = {pxp.x, pxp.y, pxp.z, pxp.w};
    const int   rA[4]   = {rv.x, rv.y, rv.z, rv.w};
    const float uxyl[4] = {ux_l, uxc.x, uxc.y, uxc.z};
    const float uxyr[4] = {uxc.y, uxc.z, uxc.w, ux_r};
    const float uyyl[4] = {uy_l, uyc.x, uyc.y, uyc.z};
    const float uyyr[4] = {uyc.y, uyc.z, uyc.w, uy_r};
    const float pyl[4]  = {p_l, pc.x, pc.y, pc.z};
    const float pyr[4]  = {pc.y, pc.z, pc.w, p_r};

    const bool irow = (i >= 1) & (i <= NXc - 2);

#pragma unroll
    for (int e = 0; e < 4; ++e) {
      const int   r    = rA[e];
      const float c_ux = uxcA[e], c_uy = uycA[e];
      const float ddx_ux = (uxpA[e] - uxmA[e]) * INV2DX;
      const float ddy_ux = (uxyr[e] - uxyl[e]) * INV2DY;
      const float ddx_uy = (uypA[e] - uymA[e]) * INV2DX;
      const float ddy_uy = (uyyr[e] - uyyl[e]) * INV2DY;

      const int j = j0 + e;
      const bool interior = (r >= 1) & irow & (j >= 1) & (j <= NYc - 2);
      if (interior) {
        const float dv    = ddx_ux + ddy_uy;
        const float d2xux = (uxpA[e] - 2.f * c_ux + uxmA[e]) * INVDX2;
        const float d2yux = (uxyr[e] - 2.f * c_ux + uxyl[e]) * INVDY2;
        const float d2xuy = (uypA[e] - 2.f * c_uy + uymA[e]) * INVDX2;
        const float d2yuy = (uyyr[e] - 2.f * c_uy + uyyl[e]) * INVDY2;
        const float ddx_p = (pxpA[e] - pxmA[e]) * INV2DX;
        const float ddy_p = (pyr[e]  - pyl[e])  * INV2DY;
        const float rx = c_ux * ddx_ux + c_uy * ddy_ux + ddx_p - NU * (d2xux + d2yux);
        const float ry = c_ux * ddx_uy + c_uy * ddy_uy + ddy_p - NU * (d2xuy + d2yuy);
        a[0] += dv * dv;
        a[1] += rx * rx;
        a[2] += ry * ry;
        a[3] += 1.f;
      }
      if ((r == 0) | (r == 2)) {            // noslip = obstacle | wall
        a[4] += c_ux * c_ux + c_uy * c_uy;
        a[5] += 1.f;
      }
      if (r == 3) {                          // inlet
        const float d = c_ux - U_INLET;
        a[6] += d * d + c_uy * c_uy;
        a[7] += 1.f;
      }
      if (r == 4) {                          // outlet
        a[8] += ddx_ux * ddx_ux;
        a[9] += 1.f;
      }
    }
  }

  // wave-64 shuffle reduction per accumulator
#pragma unroll
  for (int k = 0; k < NACC; ++k) {
    float v = a[k];
#pragma unroll
    for (int off = 32; off > 0; off >>= 1) v += __shfl_down(v, off, 64);
    a[k] = v;
  }

  __shared__ double sacc[NTHR / 64][NACC];
  const int lane = threadIdx.x & 63;
  const int wave = threadIdx.x >> 6;
  if (lane == 0) {
#pragma unroll
    for (int k = 0; k < NACC; ++k) sacc[wave][k] = (double)a[k];
  }
  __syncthreads();
  if (threadIdx.x < NACC) {
    double s = 0.0;
#pragma unroll
    for (int w = 0; w < NTHR / 64; ++w) s += sacc[w][threadIdx.x];
    partial[threadIdx.x * gridDim.x + blockIdx.x] = s;  // SoA [NACC][gridDim]
  }
}

__global__ __launch_bounds__(NTHR) void pil_finalize(const double* __restrict__ partial,
                                                     float* __restrict__ out, int nblk) {
  __shared__ double sw[NACC][NTHR / 64];
  const int t = threadIdx.x;
  const int lane = t & 63, wave = t >> 6;
#pragma unroll
  for (int k = 0; k < NACC; ++k) {
    double v = 0.0;
    for (int b = t; b < nblk; b += NTHR) v += partial[k * nblk + b];
#pragma unroll
    for (int off = 32; off > 0; off >>= 1) v += __shfl_down(v, off, 64);
    if (lane == 0) sw[k][wave] = v;
  }
  __syncthreads();
  if (t == 0) {
    double acc[NACC];
#pragma unroll
    for (int k = 0; k < NACC; ++k) {
      double s = 0.0;
#pragma unroll
      for (int w = 0; w < NTHR / 64; ++w) s += sw[k][w];
      acc[k] = s;
    }
    const double l_cont = acc[0] / fmax(acc[3], 1.0);
    const double l_mom  = (acc[1] + acc[2]) / fmax(acc[3], 1.0);
    const double l_bc   = acc[4] / fmax(acc[5], 1.0)
                        + acc[6] / fmax(acc[7], 1.0)
                        + acc[8] / fmax(acc[9], 1.0);
    const double total  = 1.0 * l_cont + 0.1 * l_mom + 1.0 * l_bc;
    out[0] = (float)l_cont;
    out[1] = (float)l_mom;
    out[2] = (float)l_bc;
    out[3] = (float)total;
  }
}

extern "C" void kernel_launch(void* const* d_in, const int* in_sizes, int n_in,
                              void* d_out, int out_size, void* d_ws, size_t ws_size,
                              hipStream_t stream) {
  const float* y   = (const float*)d_in[0];   // y_hat (16,3,1024,512) f32
  const int*   xin = (const int*)d_in[1];     // x_in  (16,2,1024,512) i32
  double* partial  = (double*)d_ws;

  int nblk = MAXBLK;
  const size_t need = (size_t)NACC * 8;
  if (ws_size < (size_t)nblk * need) {
    nblk = (int)(ws_size / need);
    if (nblk < 1) nblk = 1;
  }

  pil_main<<<nblk, NTHR, 0, stream>>>(y, xin, partial);
  pil_finalize<<<1, NTHR, 0, stream>>>(partial, (float*)d_out, nblk);
}

// Round 3
// 60.659 us; speedup vs baseline: 1.1339x; 1.0973x over previous
//
#include <hip/hip_runtime.h>

// PhysicsInformedLoss on (16,3,1024,512) f32 y_hat + (16,2,1024,512) i32 x_in.
// ~168 MB unique HBM traffic -> ~27 us floor at 6.3 TB/s.
// R3: register-rotation row march, 4-wide strip x 4 rows/thread, software-
// pipelined prefetch one row ahead, unaligned float4 loads for j-shifts.

namespace {
constexpr int NXc   = 1024;
constexpr int NYc   = 512;
constexpr int NXYc  = NXc * NYc;          // 2^19
constexpr int NBc   = 16;
constexpr int NTHR  = 256;
constexpr int NACC  = 10;
constexpr int RROWS = 4;                  // rows marched per thread
constexpr int NJG   = NYc / 4;            // 128 j-groups per row
constexpr int NCHUNK= NXc / RROWS;        // 256 row-chunks
constexpr int NBLK  = (NBc * NCHUNK * NJG) / NTHR;  // 2048 blocks, exact cover
// acc layout: 0 s_div2, 1 s_resx2, 2 s_resy2, 3 n_interior,
//             4 s_noslip, 5 n_noslip, 6 s_inlet, 7 n_inlet, 8 s_outlet, 9 n_outlet
}

typedef float f4u __attribute__((ext_vector_type(4), aligned(4)));
typedef int   i4v __attribute__((ext_vector_type(4), aligned(16)));

// L = field[j0-1 .. j0+2], R = field[j0+1 .. j0+4], edge-clamped at j=0 / j=NY-1.
__device__ __forceinline__ void load_lr(const float* __restrict__ p, int ij,
                                        bool jlo, bool jhi, f4u& L, f4u& R) {
  const f4u l = *reinterpret_cast<const f4u*>(p + ij - (jlo ? 0 : 1));
  const f4u r = *reinterpret_cast<const f4u*>(p + ij + (jhi ? 0 : 1));
  L = jlo ? (f4u){l.x, l.x, l.y, l.z} : l;   // clamp j-1 -> j at left edge
  R = jhi ? (f4u){r.y, r.z, r.w, r.w} : r;   // clamp j+4 -> j+3 at right edge
}

// aligned center [j0..j0+3] from the two shifted vectors (pure renaming)
__device__ __forceinline__ f4u ctr(f4u L, f4u R) {
  return (f4u){L.y, L.z, L.w, R.z};
}

__global__ __launch_bounds__(NTHR) void pil_main(const float* __restrict__ y,
                                                 const int* __restrict__ xin,
                                                 double* __restrict__ partial) {
  constexpr double DXd = 0.26 / 1023.0;
  constexpr double DYd = 0.12 / 511.0;
  const float INV2DX = (float)(1.0 / (2.0 * DXd));
  const float INV2DY = (float)(1.0 / (2.0 * DYd));
  const float INVDX2 = (float)(1.0 / (DXd * DXd));
  const float INVDY2 = (float)(1.0 / (DYd * DYd));
  constexpr float NU = 1e-4f;
  constexpr float U_INLET = 0.1f;

  const int tid   = blockIdx.x * NTHR + threadIdx.x;
  const int jg    = tid & (NJG - 1);          // 7 bits
  const int chunk = (tid >> 7) & (NCHUNK - 1);// 8 bits
  const int b     = tid >> 15;                // 4 bits
  const int i0    = chunk * RROWS;
  const int j0    = jg << 2;
  const bool jlo  = (jg == 0);
  const bool jhi  = (jg == NJG - 1);

  const float* __restrict__ uxp = y + (size_t)b * 3 * NXYc;
  const float* __restrict__ uyp = uxp + NXYc;
  const float* __restrict__ ppp = uxp + 2 * NXYc;
  const int*   __restrict__ rp  = xin + ((size_t)(2 * b + 1)) * NXYc;

  float a[NACC];
#pragma unroll
  for (int k = 0; k < NACC; ++k) a[k] = 0.f;

  // rotation state: prev aligned, cur L/R, next L/R per field; region vec cur/next
  f4u pAx, pAy, pAp;
  f4u cLx, cRx, cLy, cRy, cLp, cRp;
  f4u nLx, nRx, nLy, nRy, nLp, nRp;
  i4v rvC, rvN;

  {
    const int ipm = (i0 > 0) ? (i0 - 1) * NYc + j0 : j0;  // clamped halo row
    pAx = *reinterpret_cast<const f4u*>(uxp + ipm);
    pAy = *reinterpret_cast<const f4u*>(uyp + ipm);
    pAp = *reinterpret_cast<const f4u*>(ppp + ipm);
    const int o0 = i0 * NYc + j0;
    load_lr(uxp, o0, jlo, jhi, cLx, cRx);
    load_lr(uyp, o0, jlo, jhi, cLy, cRy);
    load_lr(ppp, o0, jlo, jhi, cLp, cRp);
    rvC = *reinterpret_cast<const i4v*>(rp + o0);
    const int o1 = o0 + NYc;                              // i0+1 <= 1021 always
    load_lr(uxp, o1, jlo, jhi, nLx, nRx);
    load_lr(uyp, o1, jlo, jhi, nLy, nRy);
    load_lr(ppp, o1, jlo, jhi, nLp, nRp);
    rvN = *reinterpret_cast<const i4v*>(rp + o1);
  }

#pragma unroll
  for (int s = 0; s < RROWS; ++s) {
    const int i = i0 + s;
    f4u fLx, fRx, fLy, fRy, fLp, fRp;
    i4v rvF;
    if (s < RROWS - 1) {                                  // prefetch row i+2
      const int fr = min(i + 2, NXc - 1);
      const int of = fr * NYc + j0;
      load_lr(uxp, of, jlo, jhi, fLx, fRx);
      load_lr(uyp, of, jlo, jhi, fLy, fRy);
      load_lr(ppp, of, jlo, jhi, fLp, fRp);
      rvF = *reinterpret_cast<const i4v*>(rp + of);
    }

    const f4u nAx = ctr(nLx, nRx), nAy = ctr(nLy, nRy), nAp = ctr(nLp, nRp);
    const float vux[6] = {cLx.x, cLx.y, cLx.z, cLx.w, cRx.z, cRx.w};
    const float vuy[6] = {cLy.x, cLy.y, cLy.z, cLy.w, cRy.z, cRy.w};
    const float vp [6] = {cLp.x, cLp.y, cLp.z, cLp.w, cRp.z, cRp.w};
    const int   rA [4] = {rvC.x, rvC.y, rvC.z, rvC.w};
    const bool irow = (i >= 1) & (i <= NXc - 2);

#pragma unroll
    for (int e = 0; e < 4; ++e) {
      const int   r    = rA[e];
      const float c_ux = vux[e + 1];
      const float c_uy = vuy[e + 1];
      const float ddx_ux = (nAx[e] - pAx[e]) * INV2DX;
      const float ddy_ux = (vux[e + 2] - vux[e]) * INV2DY;
      const float ddx_uy = (nAy[e] - pAy[e]) * INV2DX;
      const float ddy_uy = (vuy[e + 2] - vuy[e]) * INV2DY;

      const int j = j0 + e;
      const bool interior = (r >= 1) & irow & (j >= 1) & (j <= NYc - 2);
      if (interior) {
        const float dv    = ddx_ux + ddy_uy;
        const float d2xux = (nAx[e] - 2.f * c_ux + pAx[e]) * INVDX2;
        const float d2yux = (vux[e + 2] - 2.f * c_ux + vux[e]) * INVDY2;
        const float d2xuy = (nAy[e] - 2.f * c_uy + pAy[e]) * INVDX2;
        const float d2yuy = (vuy[e + 2] - 2.f * c_uy + vuy[e]) * INVDY2;
        const float ddx_p = (nAp[e] - pAp[e]) * INV2DX;
        const float ddy_p = (vp[e + 2] - vp[e]) * INV2DY;
        const float rx = c_ux * ddx_ux + c_uy * ddy_ux + ddx_p - NU * (d2xux + d2yux);
        const float ry = c_ux * ddx_uy + c_uy * ddy_uy + ddy_p - NU * (d2xuy + d2yuy);
        a[0] += dv * dv;
        a[1] += rx * rx;
        a[2] += ry * ry;
        a[3] += 1.f;
      }
      if ((r == 0) | (r == 2)) {            // noslip = obstacle | wall
        a[4] += c_ux * c_ux + c_uy * c_uy;
        a[5] += 1.f;
      }
      if (r == 3) {                          // inlet
        const float d = c_ux - U_INLET;
        a[6] += d * d + c_uy * c_uy;
        a[7] += 1.f;
      }
      if (r == 4) {                          // outlet
        a[8] += ddx_ux * ddx_ux;
        a[9] += 1.f;
      }
    }

    // rotate the pipeline (pure register renaming after unroll)
    pAx = ctr(cLx, cRx); pAy = ctr(cLy, cRy); pAp = ctr(cLp, cRp);
    cLx = nLx; cRx = nRx; cLy = nLy; cRy = nRy; cLp = nLp; cRp = nRp;
    nLx = fLx; nRx = fRx; nLy = fLy; nRy = fRy; nLp = fLp; nRp = fRp;
    rvC = rvN; rvN = rvF;
  }

  // wave-64 shuffle reduction per accumulator
#pragma unroll
  for (int k = 0; k < NACC; ++k) {
    float v = a[k];
#pragma unroll
    for (int off = 32; off > 0; off >>= 1) v += __shfl_down(v, off, 64);
    a[k] = v;
  }

  __shared__ double sacc[NTHR / 64][NACC];
  const int lane = threadIdx.x & 63;
  const int wave = threadIdx.x >> 6;
  if (lane == 0) {
#pragma unroll
    for (int k = 0; k < NACC; ++k) sacc[wave][k] = (double)a[k];
  }
  __syncthreads();
  if (threadIdx.x < NACC) {
    double s = 0.0;
#pragma unroll
    for (int w = 0; w < NTHR / 64; ++w) s += sacc[w][threadIdx.x];
    partial[threadIdx.x * gridDim.x + blockIdx.x] = s;  // SoA [NACC][NBLK]
  }
}

__global__ __launch_bounds__(NTHR) void pil_finalize(const double* __restrict__ partial,
                                                     float* __restrict__ out, int nblk) {
  __shared__ double sw[NACC][NTHR / 64];
  const int t = threadIdx.x;
  const int lane = t & 63, wave = t >> 6;
#pragma unroll
  for (int k = 0; k < NACC; ++k) {
    double v = 0.0;
    for (int b = t; b < nblk; b += NTHR) v += partial[k * nblk + b];
#pragma unroll
    for (int off = 32; off > 0; off >>= 1) v += __shfl_down(v, off, 64);
    if (lane == 0) sw[k][wave] = v;
  }
  __syncthreads();
  if (t == 0) {
    double acc[NACC];
#pragma unroll
    for (int k = 0; k < NACC; ++k) {
      double s = 0.0;
#pragma unroll
      for (int w = 0; w < NTHR / 64; ++w) s += sw[k][w];
      acc[k] = s;
    }
    const double l_cont = acc[0] / fmax(acc[3], 1.0);
    const double l_mom  = (acc[1] + acc[2]) / fmax(acc[3], 1.0);
    const double l_bc   = acc[4] / fmax(acc[5], 1.0)
                        + acc[6] / fmax(acc[7], 1.0)
                        + acc[8] / fmax(acc[9], 1.0);
    const double total  = 1.0 * l_cont + 0.1 * l_mom + 1.0 * l_bc;
    out[0] = (float)l_cont;
    out[1] = (float)l_mom;
    out[2] = (float)l_bc;
    out[3] = (float)total;
  }
}

extern "C" void kernel_launch(void* const* d_in, const int* in_sizes, int n_in,
                              void* d_out, int out_size, void* d_ws, size_t ws_size,
                              hipStream_t stream) {
  const float* y   = (const float*)d_in[0];   // y_hat (16,3,1024,512) f32
  const int*   xin = (const int*)d_in[1];     // x_in  (16,2,1024,512) i32
  double* partial  = (double*)d_ws;           // needs NACC*NBLK*8 = 160 KB

  pil_main<<<NBLK, NTHR, 0, stream>>>(y, xin, partial);
  pil_finalize<<<1, NTHR, 0, stream>>>(partial, (float*)d_out, NBLK);
}

// Round 4
// 48.005 us; speedup vs baseline: 1.4328x; 1.2636x over previous
//
#include <hip/hip_runtime.h>

// PhysicsInformedLoss on (16,3,1024,512) f32 y_hat + (16,2,1024,512) i32 x_in.
// R4: one wave = one full 512-col row (lane owns 8 cols, all loads aligned
// dwordx4), j-neighbors via __shfl, 8-row register-rotation march with 1-row
// prefetch. 512 blocks x 256 thr.

namespace {
constexpr int NXc   = 1024;
constexpr int NYc   = 512;
constexpr int NXYc  = NXc * NYc;
constexpr int NBc   = 16;
constexpr int NTHR  = 256;
constexpr int NACC  = 10;
constexpr int RROWS = 8;
constexpr int NCHUNK = NXc / RROWS;            // 128 row-chunks
constexpr int NWAVE  = NBc * NCHUNK;           // 2048 waves
constexpr int NBLK   = NWAVE / (NTHR / 64);    // 512 blocks
// acc: 0 s_div2, 1 s_resx2, 2 s_resy2, 3 n_interior,
//      4 s_noslip, 5 n_noslip, 6 s_inlet, 7 n_inlet, 8 s_outlet, 9 n_outlet
}

struct Frow { float4 xl, xh, yl, yh, pl, ph; };

__device__ __forceinline__ Frow ldrow(const float* __restrict__ ux,
                                      const float* __restrict__ uy,
                                      const float* __restrict__ pp, int off) {
  Frow f;
  f.xl = *reinterpret_cast<const float4*>(ux + off);
  f.xh = *reinterpret_cast<const float4*>(ux + off + 4);
  f.yl = *reinterpret_cast<const float4*>(uy + off);
  f.yh = *reinterpret_cast<const float4*>(uy + off + 4);
  f.pl = *reinterpret_cast<const float4*>(pp + off);
  f.ph = *reinterpret_cast<const float4*>(pp + off + 4);
  return f;
}

__global__ __launch_bounds__(NTHR, 2) void pil_main(const float* __restrict__ y,
                                                    const int* __restrict__ xin,
                                                    double* __restrict__ partial) {
  constexpr double DXd = 0.26 / 1023.0;
  constexpr double DYd = 0.12 / 511.0;
  const float INV2DX = (float)(1.0 / (2.0 * DXd));
  const float INV2DY = (float)(1.0 / (2.0 * DYd));
  const float INVDX2 = (float)(1.0 / (DXd * DXd));
  const float INVDY2 = (float)(1.0 / (DYd * DYd));
  constexpr float NU = 1e-4f;
  constexpr float U_INLET = 0.1f;

  const int l     = threadIdx.x & 63;
  const int wv    = (blockIdx.x << 2) | (threadIdx.x >> 6);  // 0..2047
  const int chunk = wv & (NCHUNK - 1);
  const int b     = wv >> 7;
  const int i0    = chunk * RROWS;
  const int jc    = l << 3;                                  // col base, 8/lane

  const float* __restrict__ ux = y + (size_t)b * 3 * NXYc;
  const float* __restrict__ uy = ux + NXYc;
  const float* __restrict__ pp = ux + 2 * NXYc;
  const int*   __restrict__ rp = xin + (size_t)(2 * b + 1) * NXYc;

  float a[NACC];
#pragma unroll
  for (int k = 0; k < NACC; ++k) a[k] = 0.f;

  // rotation state: prev / cur / next full rows + region codes for cur/next
  Frow P = ldrow(ux, uy, pp, (i0 > 0 ? i0 - 1 : 0) * NYc + jc);
  Frow C = ldrow(ux, uy, pp, i0 * NYc + jc);
  Frow N = ldrow(ux, uy, pp, (i0 + 1) * NYc + jc);
  int4 rCl = *reinterpret_cast<const int4*>(rp + i0 * NYc + jc);
  int4 rCh = *reinterpret_cast<const int4*>(rp + i0 * NYc + jc + 4);
  int4 rNl = *reinterpret_cast<const int4*>(rp + (i0 + 1) * NYc + jc);
  int4 rNh = *reinterpret_cast<const int4*>(rp + (i0 + 1) * NYc + jc + 4);

#pragma unroll
  for (int s = 0; s < RROWS; ++s) {
    const int i = i0 + s;

    // software-pipelined prefetch (one full compute-row of slack)
    Frow F = C;
    int4 rFl = rCl, rFh = rCh;
    if (s < RROWS - 1) F = ldrow(ux, uy, pp, min(i + 2, NXc - 1) * NYc + jc);
    if (s < RROWS - 2) {
      rFl = *reinterpret_cast<const int4*>(rp + (i + 2) * NYc + jc);
      rFh = *reinterpret_cast<const int4*>(rp + (i + 2) * NYc + jc + 4);
    }

    const float cx[8] = {C.xl.x, C.xl.y, C.xl.z, C.xl.w, C.xh.x, C.xh.y, C.xh.z, C.xh.w};
    const float cy_[8] = {C.yl.x, C.yl.y, C.yl.z, C.yl.w, C.yh.x, C.yh.y, C.yh.z, C.yh.w};
    const float cp_[8] = {C.pl.x, C.pl.y, C.pl.z, C.pl.w, C.ph.x, C.ph.y, C.ph.z, C.ph.w};
    const float pxA[8] = {P.xl.x, P.xl.y, P.xl.z, P.xl.w, P.xh.x, P.xh.y, P.xh.z, P.xh.w};
    const float pyA[8] = {P.yl.x, P.yl.y, P.yl.z, P.yl.w, P.yh.x, P.yh.y, P.yh.z, P.yh.w};
    const float ppA[8] = {P.pl.x, P.pl.y, P.pl.z, P.pl.w, P.ph.x, P.ph.y, P.ph.z, P.ph.w};
    const float nxA[8] = {N.xl.x, N.xl.y, N.xl.z, N.xl.w, N.xh.x, N.xh.y, N.xh.z, N.xh.w};
    const float nyA[8] = {N.yl.x, N.yl.y, N.yl.z, N.yl.w, N.yh.x, N.yh.y, N.yh.z, N.yh.w};
    const float npA[8] = {N.pl.x, N.pl.y, N.pl.z, N.pl.w, N.ph.x, N.ph.y, N.ph.z, N.ph.w};
    const int   rA[8]  = {rCl.x, rCl.y, rCl.z, rCl.w, rCh.x, rCh.y, rCh.z, rCh.w};

    // cur-row j-neighbors across lanes (2 shuffles per field)
    float lxx = __shfl_up(cx[7], 1, 64);   if (l == 0)  lxx = cx[0];
    float rxx = __shfl_down(cx[0], 1, 64); if (l == 63) rxx = cx[7];
    float lyy = __shfl_up(cy_[7], 1, 64);  if (l == 0)  lyy = cy_[0];
    float ryy = __shfl_down(cy_[0], 1, 64);if (l == 63) ryy = cy_[7];
    float lpp = __shfl_up(cp_[7], 1, 64);  if (l == 0)  lpp = cp_[0];
    float rpp = __shfl_down(cp_[0], 1, 64);if (l == 63) rpp = cp_[7];

    const bool irow = (i >= 1) & (i <= NXc - 2);

#pragma unroll
    for (int e = 0; e < 8; ++e) {
      const int   r    = rA[e];
      const float c_ux = cx[e], c_uy = cy_[e];
      const float uxm = (e == 0) ? lxx : cx[e - 1];
      const float uxp = (e == 7) ? rxx : cx[e + 1];
      const float uym = (e == 0) ? lyy : cy_[e - 1];
      const float uyp = (e == 7) ? ryy : cy_[e + 1];
      const float pm_ = (e == 0) ? lpp : cp_[e - 1];
      const float pp_ = (e == 7) ? rpp : cp_[e + 1];

      const float ddx_ux = (nxA[e] - pxA[e]) * INV2DX;
      const float ddy_ux = (uxp - uxm) * INV2DY;
      const float ddx_uy = (nyA[e] - pyA[e]) * INV2DX;
      const float ddy_uy = (uyp - uym) * INV2DY;

      const bool jedge = ((l == 0) & (e == 0)) | ((l == 63) & (e == 7));
      const bool interior = (r >= 1) & irow & (!jedge);
      if (interior) {
        const float dv    = ddx_ux + ddy_uy;
        const float d2xux = (nxA[e] - 2.f * c_ux + pxA[e]) * INVDX2;
        const float d2yux = (uxp - 2.f * c_ux + uxm) * INVDY2;
        const float d2xuy = (nyA[e] - 2.f * c_uy + pyA[e]) * INVDX2;
        const float d2yuy = (uyp - 2.f * c_uy + uym) * INVDY2;
        const float ddx_p = (npA[e] - ppA[e]) * INV2DX;
        const float ddy_p = (pp_ - pm_) * INV2DY;
        const float rx = c_ux * ddx_ux + c_uy * ddy_ux + ddx_p - NU * (d2xux + d2yux);
        const float ry = c_ux * ddx_uy + c_uy * ddy_uy + ddy_p - NU * (d2xuy + d2yuy);
        a[0] += dv * dv;
        a[1] += rx * rx;
        a[2] += ry * ry;
        a[3] += 1.f;
      }
      if ((r == 0) | (r == 2)) {            // noslip = obstacle | wall
        a[4] += c_ux * c_ux + c_uy * c_uy;
        a[5] += 1.f;
      }
      if (r == 3) {                          // inlet
        const float d = c_ux - U_INLET;
        a[6] += d * d + c_uy * c_uy;
        a[7] += 1.f;
      }
      if (r == 4) {                          // outlet
        a[8] += ddx_ux * ddx_ux;
        a[9] += 1.f;
      }
    }

    if (s < RROWS - 1) {   // rotate pipeline (register renaming)
      P = C; C = N; N = F;
      rCl = rNl; rCh = rNh; rNl = rFl; rNh = rFh;
    }
  }

  // wave-64 shuffle reduction per accumulator
#pragma unroll
  for (int k = 0; k < NACC; ++k) {
    float v = a[k];
#pragma unroll
    for (int off = 32; off > 0; off >>= 1) v += __shfl_down(v, off, 64);
    a[k] = v;
  }

  __shared__ double sacc[NTHR / 64][NACC];
  const int lane = threadIdx.x & 63;
  const int wave = threadIdx.x >> 6;
  if (lane == 0) {
#pragma unroll
    for (int k = 0; k < NACC; ++k) sacc[wave][k] = (double)a[k];
  }
  __syncthreads();
  if (threadIdx.x < NACC) {
    double s = 0.0;
#pragma unroll
    for (int w = 0; w < NTHR / 64; ++w) s += sacc[w][threadIdx.x];
    partial[threadIdx.x * gridDim.x + blockIdx.x] = s;  // SoA [NACC][NBLK]
  }
}

__global__ __launch_bounds__(NTHR) void pil_finalize(const double* __restrict__ partial,
                                                     float* __restrict__ out, int nblk) {
  __shared__ double sw[NACC][NTHR / 64];
  const int t = threadIdx.x;
  const int lane = t & 63, wave = t >> 6;
#pragma unroll
  for (int k = 0; k < NACC; ++k) {
    double v = 0.0;
    for (int b = t; b < nblk; b += NTHR) v += partial[k * nblk + b];
#pragma unroll
    for (int off = 32; off > 0; off >>= 1) v += __shfl_down(v, off, 64);
    if (lane == 0) sw[k][wave] = v;
  }
  __syncthreads();
  if (t == 0) {
    double acc[NACC];
#pragma unroll
    for (int k = 0; k < NACC; ++k) {
      double s = 0.0;
#pragma unroll
      for (int w = 0; w < NTHR / 64; ++w) s += sw[k][w];
      acc[k] = s;
    }
    const double l_cont = acc[0] / fmax(acc[3], 1.0);
    const double l_mom  = (acc[1] + acc[2]) / fmax(acc[3], 1.0);
    const double l_bc   = acc[4] / fmax(acc[5], 1.0)
                        + acc[6] / fmax(acc[7], 1.0)
                        + acc[8] / fmax(acc[9], 1.0);
    const double total  = 1.0 * l_cont + 0.1 * l_mom + 1.0 * l_bc;
    out[0] = (float)l_cont;
    out[1] = (float)l_mom;
    out[2] = (float)l_bc;
    out[3] = (float)total;
  }
}

extern "C" void kernel_launch(void* const* d_in, const int* in_sizes, int n_in,
                              void* d_out, int out_size, void* d_ws, size_t ws_size,
                              hipStream_t stream) {
  const float* y   = (const float*)d_in[0];   // y_hat (16,3,1024,512) f32
  const int*   xin = (const int*)d_in[1];     // x_in  (16,2,1024,512) i32
  double* partial  = (double*)d_ws;           // NACC*NBLK*8 = 40 KB

  pil_main<<<NBLK, NTHR, 0, stream>>>(y, xin, partial);
  pil_finalize<<<1, NTHR, 0, stream>>>(partial, (float*)d_out, NBLK);
}